// Round 6
// baseline (392.499 us; speedup 1.0000x reference)
//
#include <hip/hip_runtime.h>

#define N_NODES 50000
#define N_EDGES 800000
#define D 128
#define TSTR 136              // LDS row stride in bf16 elems (272B: 16B-aligned)
#define SCAN_BLOCKS 196       // ceil(50000/256)

typedef __attribute__((ext_vector_type(8))) short bf16x8;
typedef __attribute__((ext_vector_type(4))) float f32x4;

__device__ __forceinline__ unsigned short f32_to_bf16_rne(float f) {
    unsigned u = __float_as_uint(f);
    u += 0x7fffu + ((u >> 16) & 1u);
    return (unsigned short)(u >> 16);
}

__device__ __forceinline__ void acc_bf16x4(uint2 r, float& x, float& y, float& z, float& w) {
    x += __uint_as_float(r.x << 16);
    y += __uint_as_float(r.x & 0xffff0000u);
    z += __uint_as_float(r.y << 16);
    w += __uint_as_float(r.y & 0xffff0000u);
}

// ---------------------------------------------------------------------------
// prep: rank[e] = position of edge e within its dst bucket (histogram atomic's
// old value)  AND  x fp32 -> bf16 (8 elems/thread; 800K threads covers both)
// ---------------------------------------------------------------------------
__global__ void prep_kernel(const int* __restrict__ dst, int* __restrict__ counts,
                            int* __restrict__ rank,
                            const float* __restrict__ x, unsigned short* __restrict__ xb) {
    const int t = blockIdx.x * blockDim.x + threadIdx.x;
    if (t < N_EDGES) {
        rank[t] = atomicAdd(&counts[dst[t]], 1);
    }
    {
        const float4 v0 = *(const float4*)(x + (size_t)t * 8);
        const float4 v1 = *(const float4*)(x + (size_t)t * 8 + 4);
        uint4 p;
        p.x = (unsigned)f32_to_bf16_rne(v0.x) | ((unsigned)f32_to_bf16_rne(v0.y) << 16);
        p.y = (unsigned)f32_to_bf16_rne(v0.z) | ((unsigned)f32_to_bf16_rne(v0.w) << 16);
        p.z = (unsigned)f32_to_bf16_rne(v1.x) | ((unsigned)f32_to_bf16_rne(v1.y) << 16);
        p.w = (unsigned)f32_to_bf16_rne(v1.z) | ((unsigned)f32_to_bf16_rne(v1.w) << 16);
        *(uint4*)(xb + (size_t)t * 8) = p;
    }
}

// ---------------------------------------------------------------------------
// Scan A: per-block (256-wide) sums of counts -> bsum[196]
// ---------------------------------------------------------------------------
__global__ void block_sum_kernel(const int* __restrict__ counts, int* __restrict__ bsum) {
    __shared__ int red[256];
    const int tid = threadIdx.x;
    const int i = blockIdx.x * 256 + tid;
    red[tid] = (i < N_NODES) ? counts[i] : 0;
    __syncthreads();
    for (int s = 128; s > 0; s >>= 1) {
        if (tid < s) red[tid] += red[tid + s];
        __syncthreads();
    }
    if (tid == 0) bsum[blockIdx.x] = red[0];
}

// ---------------------------------------------------------------------------
// Scan B: exclusive scan of the 196 block sums (single tiny block)
// ---------------------------------------------------------------------------
__global__ void bsum_scan_kernel(const int* __restrict__ bsum,
                                 int* __restrict__ bpre,
                                 int* __restrict__ offsets) {
    __shared__ int s[256];
    const int tid = threadIdx.x;
    const int v = (tid < SCAN_BLOCKS) ? bsum[tid] : 0;
    s[tid] = v;
    __syncthreads();
    for (int off = 1; off < 256; off <<= 1) {
        int a = (tid >= off) ? s[tid - off] : 0;
        __syncthreads();
        s[tid] += a;
        __syncthreads();
    }
    bpre[tid] = s[tid] - v;
    if (tid == 255) offsets[N_NODES] = s[255];
}

// ---------------------------------------------------------------------------
// Scan C (blocks 0..195): per-block exclusive scan + block prefix -> offsets
// wfrag (blocks 196..387): pack all 3 weights as bf16 MFMA B-fragments.
//   B[k][n] for tile nt, chunk kc at Wb[((w*8+nt)*4+kc)*512 + lane*8 + j],
//   lane = quad*16+n, k = kc*32+quad*8+j, B[k][n] = W[nt*16+n][k].
// ---------------------------------------------------------------------------
__global__ void offsets_wfrag_kernel(const int* __restrict__ counts,
                                     const int* __restrict__ bpre,
                                     int* __restrict__ offsets,
                                     const float* __restrict__ W1,
                                     const float* __restrict__ W2,
                                     const float* __restrict__ W3,
                                     unsigned short* __restrict__ Wb) {
    if (blockIdx.x < SCAN_BLOCKS) {
        __shared__ int s[256];
        const int tid = threadIdx.x;
        const int i = blockIdx.x * 256 + tid;
        const int v = (i < N_NODES) ? counts[i] : 0;
        s[tid] = v;
        __syncthreads();
        for (int off = 1; off < 256; off <<= 1) {
            int a = (tid >= off) ? s[tid - off] : 0;
            __syncthreads();
            s[tid] += a;
            __syncthreads();
        }
        const int excl = s[tid] - v + bpre[blockIdx.x];
        if (i < N_NODES) offsets[i] = excl;
    } else {
        const int unit = (blockIdx.x - SCAN_BLOCKS) * 2 + (threadIdx.x >> 7); // 0..383
        const int w = unit >> 7;
        const int o = unit & 127;
        const int k = threadIdx.x & 127;
        const float* W = (w == 0) ? W1 : (w == 1) ? W2 : W3;
        const unsigned short v = f32_to_bf16_rne(W[o * D + k]);
        const int nt = o >> 4, n = o & 15;
        const int kc = k >> 5, kr = k & 31, quad = kr >> 3, j = kr & 7;
        const int lane = quad * 16 + n;
        Wb[(((size_t)w * 8 + nt) * 4 + kc) * 512 + lane * 8 + j] = v;
    }
}

// ---------------------------------------------------------------------------
// CSR fill, atomic-free: p = offsets[dst[e]] + rank[e]
// ---------------------------------------------------------------------------
__global__ void fill_kernel(const int* __restrict__ src, const int* __restrict__ dst,
                            const int* __restrict__ rank,
                            const int* __restrict__ offsets, int* __restrict__ esrc) {
    int e = blockIdx.x * blockDim.x + threadIdx.x;
    if (e < N_EDGES) {
        esrc[offsets[dst[e]] + rank[e]] = src[e];
    }
}

// ---------------------------------------------------------------------------
// Gather (K-split): block bid -> (node group ng, K-quarter ky) with
//   ky = (bid & 7) >> 1  so (assuming bid%8 -> XCD round-robin) each XCD
//   touches only ONE 3.2MB quarter-slice of hb -> L2-resident.
// Wave = 1 node; 8 lanes/edge (8B = 4 bf16 dims each, 64B line per edge);
//   8 edges in flight per instruction, unroll x2 = 16 edges/iter.
//   Indices pre-loaded coalesced + shfl-broadcast. Butterfly (8,16,32)
//   reduces edge-slots; lanes g==0 write the t quarter-row (bf16).
//   t[v] = sum_src h[src] - deg*h[v]
// ---------------------------------------------------------------------------
__global__ __launch_bounds__(256) void gather_kernel(
    const unsigned short* __restrict__ hb,     // [N][D] bf16
    const int* __restrict__ offsets,
    const int* __restrict__ esrc,
    unsigned short* __restrict__ tg) {         // [N][D] bf16 out

    const int bid = blockIdx.x;
    const int ky = (bid & 7) >> 1;                   // XCD-pinned quarter
    const int ng = ((bid >> 3) << 1) + (bid & 1);    // 0..12499
    const int wave = threadIdx.x >> 6;
    const int lane = threadIdx.x & 63;
    const int g = lane >> 3;          // edge slot 0..7
    const int d = lane & 7;           // dim-lane: dims col..col+3
    const int v = ng * 4 + wave;
    const int col = ky * 32 + d * 4;

    const int beg = offsets[v];
    const int deg = offsets[v + 1] - beg;

    float ax = 0.f, ay = 0.f, az = 0.f, aw = 0.f;
    float bx = 0.f, by = 0.f, bz = 0.f, bw = 0.f;

    for (int base = 0; base < deg; base += 64) {
        const int cnt = min(deg - base, 64);
        int myidx = 0;
        if (lane < cnt) myidx = esrc[beg + base + lane];

        for (int i = 0; i < cnt; i += 16) {
            const int e0 = i + g;
            const int e1 = i + 8 + g;
            const int s0 = __shfl(myidx, e0, 64);
            const int s1 = __shfl(myidx, e1, 64);
            if (e0 < cnt) {
                const uint2 r = *(const uint2*)(hb + (size_t)s0 * D + col);
                acc_bf16x4(r, ax, ay, az, aw);
            }
            if (e1 < cnt) {
                const uint2 r = *(const uint2*)(hb + (size_t)s1 * D + col);
                acc_bf16x4(r, bx, by, bz, bw);
            }
        }
    }
    ax += bx; ay += by; az += bz; aw += bw;

    // reduce across the 8 edge slots (lanes sharing d)
#pragma unroll
    for (int m = 8; m <= 32; m <<= 1) {
        ax += __shfl_xor(ax, m, 64);
        ay += __shfl_xor(ay, m, 64);
        az += __shfl_xor(az, m, 64);
        aw += __shfl_xor(aw, m, 64);
    }

    if (g == 0) {
        const float dv = (float)deg;
        const uint2 r = *(const uint2*)(hb + (size_t)v * D + col);
        const float tx = ax - dv * __uint_as_float(r.x << 16);
        const float ty = ay - dv * __uint_as_float(r.x & 0xffff0000u);
        const float tz = az - dv * __uint_as_float(r.y << 16);
        const float tw = aw - dv * __uint_as_float(r.y & 0xffff0000u);
        unsigned p0 = (unsigned)f32_to_bf16_rne(tx) | ((unsigned)f32_to_bf16_rne(ty) << 16);
        unsigned p1 = (unsigned)f32_to_bf16_rne(tz) | ((unsigned)f32_to_bf16_rne(tw) << 16);
        *(uint2*)(tg + (size_t)v * D + col) = make_uint2(p0, p1);
    }
}

// ---------------------------------------------------------------------------
// GEMM: out[16][128] = t[16][128] @ W^T[128][128] + deg ⊗ b
// Stage t tile via one coalesced uint4/thread; 8 v_mfma_f32_16x16x32_bf16/wave.
// ---------------------------------------------------------------------------
template <bool OUT_BF16>
__global__ __launch_bounds__(256) void gemm_kernel(
    const unsigned short* __restrict__ tg,     // [N][D] bf16
    const int* __restrict__ offsets,
    const unsigned short* __restrict__ Wb,     // fragment-ordered bf16 (this layer)
    const float* __restrict__ bias,
    float* __restrict__ outf,
    unsigned short* __restrict__ outb) {

    __shared__ __align__(16) unsigned short tb[16][TSTR];
    __shared__ float degf[16];

    const int tid = threadIdx.x;
    const int vbase = blockIdx.x * 16;

    {   // stage t tile: 256 threads x 16B = 4KB coalesced
        const int row = tid >> 4;
        const int c8 = (tid & 15) * 8;
        *(uint4*)&tb[row][c8] = *(const uint4*)(tg + (size_t)(vbase + row) * D + c8);
    }
    if (tid < 16) degf[tid] = (float)(offsets[vbase + tid + 1] - offsets[vbase + tid]);
    __syncthreads();

    const int wave = tid >> 6;
    const int lane = tid & 63;
    const int n16 = lane & 15;
    const int quad = lane >> 4;

    bf16x8 afrag[4];
#pragma unroll
    for (int kc = 0; kc < 4; ++kc)
        afrag[kc] = *(const bf16x8*)&tb[n16][kc * 32 + quad * 8];

#pragma unroll
    for (int i = 0; i < 2; ++i) {
        const int nt = wave * 2 + i;
        f32x4 acc = {0.f, 0.f, 0.f, 0.f};
#pragma unroll
        for (int kc = 0; kc < 4; ++kc) {
            const bf16x8 bfrag = *(const bf16x8*)&Wb[((nt * 4 + kc) * 64 + lane) * 8];
            acc = __builtin_amdgcn_mfma_f32_16x16x32_bf16(afrag[kc], bfrag, acc, 0, 0, 0);
        }
        const int o = nt * 16 + n16;
        const float bo = bias[o];
#pragma unroll
        for (int r = 0; r < 4; ++r) {
            const int m = quad * 4 + r;
            const float val = acc[r] + degf[m] * bo;
            if (OUT_BF16)
                outb[(size_t)(vbase + m) * D + o] = f32_to_bf16_rne(val);
            else
                outf[(size_t)(vbase + m) * D + o] = val;
        }
    }
}

extern "C" void kernel_launch(void* const* d_in, const int* in_sizes, int n_in,
                              void* d_out, int out_size, void* d_ws, size_t ws_size,
                              hipStream_t stream) {
    const float* x  = (const float*)d_in[0];
    const float* W1 = (const float*)d_in[1];
    const float* b1 = (const float*)d_in[2];
    const float* W2 = (const float*)d_in[3];
    const float* b2 = (const float*)d_in[4];
    const float* W3 = (const float*)d_in[5];
    const float* b3 = (const float*)d_in[6];
    const int*   ei = (const int*)d_in[7];      // [2, E] int32
    // d_in[8] = edge_index_inter — unused by the reference

    const int* src = ei;            // row 0
    const int* dst = ei + N_EDGES;  // row 1
    float* out = (float*)d_out;

    // workspace layout (256B-aligned slabs)
    char* ws = (char*)d_ws;
    int* counts  = (int*)ws;                      ws += 204800;               // N ints
    int* offsets = (int*)ws;                      ws += 204800;               // N+1 ints
    int* bsum    = (int*)ws;                      ws += 1024;
    int* bpre    = (int*)ws;                      ws += 1024;
    int* rank    = (int*)ws;                      ws += (size_t)N_EDGES * 4;  // 3.2MB
    int* esrc    = (int*)ws;                      ws += (size_t)N_EDGES * 4;  // 3.2MB
    unsigned short* Wb = (unsigned short*)ws;     ws += 3 * 16384 * 2;        // 96KB
    unsigned short* xb = (unsigned short*)ws;     ws += (size_t)N_NODES * D * 2;
    unsigned short* h1 = (unsigned short*)ws;     ws += (size_t)N_NODES * D * 2;
    unsigned short* h2 = (unsigned short*)ws;     ws += (size_t)N_NODES * D * 2;
    unsigned short* tg = (unsigned short*)ws;     ws += (size_t)N_NODES * D * 2;

    // ---- CSR build + cvt + weight pack ----
    hipMemsetAsync(counts, 0, N_NODES * sizeof(int), stream);
    prep_kernel<<<(N_EDGES + 255) / 256, 256, 0, stream>>>(dst, counts, rank, x, xb);
    block_sum_kernel<<<SCAN_BLOCKS, 256, 0, stream>>>(counts, bsum);
    bsum_scan_kernel<<<1, 256, 0, stream>>>(bsum, bpre, offsets);
    offsets_wfrag_kernel<<<SCAN_BLOCKS + 192, 256, 0, stream>>>(counts, bpre, offsets,
                                                                W1, W2, W3, Wb);
    fill_kernel<<<(N_EDGES + 255) / 256, 256, 0, stream>>>(src, dst, rank, offsets, esrc);

    const int gblocks = (N_NODES / 4) * 4;   // 50000: (ng, ky) pairs
    const int mblocks = N_NODES / 16;        // 3125

    // layer 1
    gather_kernel<<<gblocks, 256, 0, stream>>>(xb, offsets, esrc, tg);
    gemm_kernel<true ><<<mblocks, 256, 0, stream>>>(tg, offsets, Wb,         b1, nullptr, h1);
    // layer 2
    gather_kernel<<<gblocks, 256, 0, stream>>>(h1, offsets, esrc, tg);
    gemm_kernel<true ><<<mblocks, 256, 0, stream>>>(tg, offsets, Wb + 16384, b2, nullptr, h2);
    // layer 3
    gather_kernel<<<gblocks, 256, 0, stream>>>(h2, offsets, esrc, tg);
    gemm_kernel<false><<<mblocks, 256, 0, stream>>>(tg, offsets, Wb + 32768, b3, out, nullptr);
}

// Round 7
// 272.021 us; speedup vs baseline: 1.4429x; 1.4429x over previous
//
#include <hip/hip_runtime.h>

#define N_NODES 50000
#define N_EDGES 800000
#define D 128
#define TN 16                 // nodes per block in the fused layer kernel
#define TSTR 136              // LDS row stride in bf16 elems (272B: 16B-aligned)
#define SCAN_BLOCKS 196       // ceil(50000/256)

typedef __attribute__((ext_vector_type(8))) short bf16x8;
typedef __attribute__((ext_vector_type(4))) float f32x4;

__device__ __forceinline__ unsigned short f32_to_bf16_rne(float f) {
    unsigned u = __float_as_uint(f);
    u += 0x7fffu + ((u >> 16) & 1u);
    return (unsigned short)(u >> 16);
}

__device__ __forceinline__ void acc_bf16x4(uint2 r, float& x, float& y, float& z, float& w) {
    x += __uint_as_float(r.x << 16);
    y += __uint_as_float(r.x & 0xffff0000u);
    z += __uint_as_float(r.y << 16);
    w += __uint_as_float(r.y & 0xffff0000u);
}

// U edge-pairs (2U edges) starting at i: 8 lanes... (lanes 0-31: even edge,
// lanes 32-63: odd edge). U independent uint2 loads per thread in flight.
template <int U>
__device__ __forceinline__ void gather_phase(const unsigned short* __restrict__ hb,
                                             int myidx, int i, int sub, int q,
                                             float* ax, float* ay, float* az, float* aw) {
    int si[U];
    uint2 rr[U];
#pragma unroll
    for (int u = 0; u < U; ++u) si[u] = __shfl(myidx, i + 2 * u + sub, 64);
#pragma unroll
    for (int u = 0; u < U; ++u) rr[u] = *(const uint2*)(hb + (size_t)si[u] * D + 4 * q);
#pragma unroll
    for (int u = 0; u < U; ++u)
        acc_bf16x4(rr[u], ax[u & 3], ay[u & 3], az[u & 3], aw[u & 3]);
}

// ---------------------------------------------------------------------------
// prep: rank[e] = position of edge e within its dst bucket (histogram atomic's
// old value)  AND  x fp32 -> bf16 (8 elems/thread; 800K threads covers both)
// ---------------------------------------------------------------------------
__global__ void prep_kernel(const int* __restrict__ dst, int* __restrict__ counts,
                            int* __restrict__ rank,
                            const float* __restrict__ x, unsigned short* __restrict__ xb) {
    const int t = blockIdx.x * blockDim.x + threadIdx.x;
    if (t < N_EDGES) {
        rank[t] = atomicAdd(&counts[dst[t]], 1);
    }
    {
        const float4 v0 = *(const float4*)(x + (size_t)t * 8);
        const float4 v1 = *(const float4*)(x + (size_t)t * 8 + 4);
        uint4 p;
        p.x = (unsigned)f32_to_bf16_rne(v0.x) | ((unsigned)f32_to_bf16_rne(v0.y) << 16);
        p.y = (unsigned)f32_to_bf16_rne(v0.z) | ((unsigned)f32_to_bf16_rne(v0.w) << 16);
        p.z = (unsigned)f32_to_bf16_rne(v1.x) | ((unsigned)f32_to_bf16_rne(v1.y) << 16);
        p.w = (unsigned)f32_to_bf16_rne(v1.z) | ((unsigned)f32_to_bf16_rne(v1.w) << 16);
        *(uint4*)(xb + (size_t)t * 8) = p;
    }
}

// ---------------------------------------------------------------------------
// Scan A: per-block (256-wide) sums of counts -> bsum[196]
// ---------------------------------------------------------------------------
__global__ void block_sum_kernel(const int* __restrict__ counts, int* __restrict__ bsum) {
    __shared__ int red[256];
    const int tid = threadIdx.x;
    const int i = blockIdx.x * 256 + tid;
    red[tid] = (i < N_NODES) ? counts[i] : 0;
    __syncthreads();
    for (int s = 128; s > 0; s >>= 1) {
        if (tid < s) red[tid] += red[tid + s];
        __syncthreads();
    }
    if (tid == 0) bsum[blockIdx.x] = red[0];
}

// ---------------------------------------------------------------------------
// Scan B: exclusive scan of the 196 block sums (single tiny block)
// ---------------------------------------------------------------------------
__global__ void bsum_scan_kernel(const int* __restrict__ bsum,
                                 int* __restrict__ bpre,
                                 int* __restrict__ offsets) {
    __shared__ int s[256];
    const int tid = threadIdx.x;
    const int v = (tid < SCAN_BLOCKS) ? bsum[tid] : 0;
    s[tid] = v;
    __syncthreads();
    for (int off = 1; off < 256; off <<= 1) {
        int a = (tid >= off) ? s[tid - off] : 0;
        __syncthreads();
        s[tid] += a;
        __syncthreads();
    }
    bpre[tid] = s[tid] - v;
    if (tid == 255) offsets[N_NODES] = s[255];
}

// ---------------------------------------------------------------------------
// Scan C (blocks 0..195): per-block exclusive scan + block prefix -> offsets
// wfrag (blocks 196..387): pack all 3 weights as bf16 MFMA B-fragments.
//   B[k][n] for tile nt, chunk kc at Wb[((w*8+nt)*4+kc)*512 + lane*8 + j],
//   lane = quad*16+n, k = kc*32+quad*8+j, B[k][n] = W[nt*16+n][k].
// ---------------------------------------------------------------------------
__global__ void offsets_wfrag_kernel(const int* __restrict__ counts,
                                     const int* __restrict__ bpre,
                                     int* __restrict__ offsets,
                                     const float* __restrict__ W1,
                                     const float* __restrict__ W2,
                                     const float* __restrict__ W3,
                                     unsigned short* __restrict__ Wb) {
    if (blockIdx.x < SCAN_BLOCKS) {
        __shared__ int s[256];
        const int tid = threadIdx.x;
        const int i = blockIdx.x * 256 + tid;
        const int v = (i < N_NODES) ? counts[i] : 0;
        s[tid] = v;
        __syncthreads();
        for (int off = 1; off < 256; off <<= 1) {
            int a = (tid >= off) ? s[tid - off] : 0;
            __syncthreads();
            s[tid] += a;
            __syncthreads();
        }
        const int excl = s[tid] - v + bpre[blockIdx.x];
        if (i < N_NODES) offsets[i] = excl;
    } else {
        const int unit = (blockIdx.x - SCAN_BLOCKS) * 2 + (threadIdx.x >> 7); // 0..383
        const int w = unit >> 7;
        const int o = unit & 127;
        const int k = threadIdx.x & 127;
        const float* W = (w == 0) ? W1 : (w == 1) ? W2 : W3;
        const unsigned short v = f32_to_bf16_rne(W[o * D + k]);
        const int nt = o >> 4, n = o & 15;
        const int kc = k >> 5, kr = k & 31, quad = kr >> 3, j = kr & 7;
        const int lane = quad * 16 + n;
        Wb[(((size_t)w * 8 + nt) * 4 + kc) * 512 + lane * 8 + j] = v;
    }
}

// ---------------------------------------------------------------------------
// CSR fill, atomic-free: p = offsets[dst[e]] + rank[e]
// ---------------------------------------------------------------------------
__global__ void fill_kernel(const int* __restrict__ src, const int* __restrict__ dst,
                            const int* __restrict__ rank,
                            const int* __restrict__ offsets, int* __restrict__ esrc) {
    int e = blockIdx.x * blockDim.x + threadIdx.x;
    if (e < N_EDGES) {
        esrc[offsets[dst[e]] + rank[e]] = src[e];
    }
}

// ---------------------------------------------------------------------------
// Fused layer: out[v] = (sum h[src_e] - deg[v]*h[v]) @ W^T + deg[v]*b
// Phase 1 gather: per node, one coalesced load pulls <=64 edge indices into
//   per-lane regs, shfl-broadcast (no dependent index loads). Main body does
//   16 edges/iter = 8 independent uint2 row-loads in flight per thread into
//   4 accumulator sets; remainder phases 8/4/2/1 keep depth up for mid-degree
//   nodes. Edge pairing across half-waves; shfl_xor(32) combine; t -> LDS bf16.
// Phase 2: 16x128x128 GEMM via 8 v_mfma_f32_16x16x32_bf16 per wave.
// ---------------------------------------------------------------------------
template <bool OUT_BF16>
__global__ __launch_bounds__(256) void gnn_layer_kernel(
    const unsigned short* __restrict__ hb,     // [N][D] bf16
    const int* __restrict__ offsets,
    const int* __restrict__ esrc,
    const unsigned short* __restrict__ Wb,     // fragment-ordered bf16 (this layer)
    const float* __restrict__ bias,
    float* __restrict__ outf,
    unsigned short* __restrict__ outb) {

    __shared__ __align__(16) unsigned short tb[TN][TSTR];
    __shared__ float degf[TN];

    const int tid = threadIdx.x;
    const int wave = tid >> 6;
    const int lane = tid & 63;
    const int sub = lane >> 5;        // edge parity within pair
    const int q = lane & 31;          // dim group: dims 4q..4q+3
    const int vbase = blockIdx.x * TN;

    // ---- phase 1: gather ----
    for (int j = wave * 4; j < wave * 4 + 4; ++j) {
        const int v = vbase + j;
        const int beg = offsets[v];
        const int deg = offsets[v + 1] - beg;

        float ax[4] = {0.f, 0.f, 0.f, 0.f};
        float ay[4] = {0.f, 0.f, 0.f, 0.f};
        float az[4] = {0.f, 0.f, 0.f, 0.f};
        float aw[4] = {0.f, 0.f, 0.f, 0.f};

        for (int base = 0; base < deg; base += 64) {
            const int cnt = min(deg - base, 64);
            int myidx = 0;
            if (lane < cnt) myidx = esrc[beg + base + lane];

            int i = 0;
            for (; i + 16 <= cnt; i += 16)
                gather_phase<8>(hb, myidx, i, sub, q, ax, ay, az, aw);
            if (i + 8 <= cnt) {
                gather_phase<4>(hb, myidx, i, sub, q, ax, ay, az, aw);
                i += 8;
            }
            if (i + 4 <= cnt) {
                gather_phase<2>(hb, myidx, i, sub, q, ax, ay, az, aw);
                i += 4;
            }
            if (i + 2 <= cnt) {
                gather_phase<1>(hb, myidx, i, sub, q, ax, ay, az, aw);
                i += 2;
            }
            if (i < cnt) {                       // odd tail: only sub==0 loads
                const int s0 = __shfl(myidx, i, 64);
                if (sub == 0) {
                    const uint2 r = *(const uint2*)(hb + (size_t)s0 * D + 4 * q);
                    acc_bf16x4(r, ax[0], ay[0], az[0], aw[0]);
                }
            }
        }

        float sx = (ax[0] + ax[1]) + (ax[2] + ax[3]);
        float sy = (ay[0] + ay[1]) + (ay[2] + ay[3]);
        float sz = (az[0] + az[1]) + (az[2] + az[3]);
        float sw = (aw[0] + aw[1]) + (aw[2] + aw[3]);

        sx += __shfl_xor(sx, 32, 64);
        sy += __shfl_xor(sy, 32, 64);
        sz += __shfl_xor(sz, 32, 64);
        sw += __shfl_xor(sw, 32, 64);

        const float dv = (float)deg;
        if (sub == 0) {
            const uint2 r = *(const uint2*)(hb + (size_t)v * D + 4 * q);
            const float tx = sx - dv * __uint_as_float(r.x << 16);
            const float ty = sy - dv * __uint_as_float(r.x & 0xffff0000u);
            const float tz = sz - dv * __uint_as_float(r.y << 16);
            const float tw = sw - dv * __uint_as_float(r.y & 0xffff0000u);
            unsigned p0 = (unsigned)f32_to_bf16_rne(tx) | ((unsigned)f32_to_bf16_rne(ty) << 16);
            unsigned p1 = (unsigned)f32_to_bf16_rne(tz) | ((unsigned)f32_to_bf16_rne(tw) << 16);
            *(uint2*)&tb[j][4 * q] = make_uint2(p0, p1);
        }
        if (lane == 0) degf[j] = dv;
    }
    __syncthreads();

    // ---- phase 2: MFMA GEMM  out[16][128] = t[16][128] @ Wt[128][128] ----
    const int n16 = lane & 15;
    const int quad = lane >> 4;

    bf16x8 afrag[4];
#pragma unroll
    for (int kc = 0; kc < 4; ++kc)
        afrag[kc] = *(const bf16x8*)&tb[n16][kc * 32 + quad * 8];

#pragma unroll
    for (int i = 0; i < 2; ++i) {
        const int nt = wave * 2 + i;
        f32x4 acc = {0.f, 0.f, 0.f, 0.f};
#pragma unroll
        for (int kc = 0; kc < 4; ++kc) {
            const bf16x8 bfrag = *(const bf16x8*)&Wb[((nt * 4 + kc) * 64 + lane) * 8];
            acc = __builtin_amdgcn_mfma_f32_16x16x32_bf16(afrag[kc], bfrag, acc, 0, 0, 0);
        }
        const int o = nt * 16 + n16;
        const float bo = bias[o];
#pragma unroll
        for (int r = 0; r < 4; ++r) {
            const int m = quad * 4 + r;
            const float val = acc[r] + degf[m] * bo;
            if (OUT_BF16)
                outb[(size_t)(vbase + m) * D + o] = f32_to_bf16_rne(val);
            else
                outf[(size_t)(vbase + m) * D + o] = val;
        }
    }
}

extern "C" void kernel_launch(void* const* d_in, const int* in_sizes, int n_in,
                              void* d_out, int out_size, void* d_ws, size_t ws_size,
                              hipStream_t stream) {
    const float* x  = (const float*)d_in[0];
    const float* W1 = (const float*)d_in[1];
    const float* b1 = (const float*)d_in[2];
    const float* W2 = (const float*)d_in[3];
    const float* b2 = (const float*)d_in[4];
    const float* W3 = (const float*)d_in[5];
    const float* b3 = (const float*)d_in[6];
    const int*   ei = (const int*)d_in[7];      // [2, E] int32
    // d_in[8] = edge_index_inter — unused by the reference

    const int* src = ei;            // row 0
    const int* dst = ei + N_EDGES;  // row 1
    float* out = (float*)d_out;

    // workspace layout (256B-aligned slabs)
    char* ws = (char*)d_ws;
    int* counts  = (int*)ws;                      ws += 204800;               // N ints
    int* offsets = (int*)ws;                      ws += 204800;               // N+1 ints
    int* bsum    = (int*)ws;                      ws += 1024;
    int* bpre    = (int*)ws;                      ws += 1024;
    int* rank    = (int*)ws;                      ws += (size_t)N_EDGES * 4;  // 3.2MB
    int* esrc    = (int*)ws;                      ws += (size_t)N_EDGES * 4;  // 3.2MB
    unsigned short* Wb = (unsigned short*)ws;     ws += 3 * 16384 * 2;        // 96KB
    unsigned short* xb = (unsigned short*)ws;     ws += (size_t)N_NODES * D * 2;
    unsigned short* h1 = (unsigned short*)ws;     ws += (size_t)N_NODES * D * 2;
    unsigned short* h2 = (unsigned short*)ws;

    // ---- CSR build + cvt + weight pack ----
    hipMemsetAsync(counts, 0, N_NODES * sizeof(int), stream);
    prep_kernel<<<(N_EDGES + 255) / 256, 256, 0, stream>>>(dst, counts, rank, x, xb);
    block_sum_kernel<<<SCAN_BLOCKS, 256, 0, stream>>>(counts, bsum);
    bsum_scan_kernel<<<1, 256, 0, stream>>>(bsum, bpre, offsets);
    offsets_wfrag_kernel<<<SCAN_BLOCKS + 192, 256, 0, stream>>>(counts, bpre, offsets,
                                                                W1, W2, W3, Wb);
    fill_kernel<<<(N_EDGES + 255) / 256, 256, 0, stream>>>(src, dst, rank, offsets, esrc);

    const int blocks = N_NODES / TN;   // 3125

    gnn_layer_kernel<true ><<<blocks, 256, 0, stream>>>(xb, offsets, esrc, Wb,          b1, nullptr, h1);
    gnn_layer_kernel<true ><<<blocks, 256, 0, stream>>>(h1, offsets, esrc, Wb + 16384,  b2, nullptr, h2);
    gnn_layer_kernel<false><<<blocks, 256, 0, stream>>>(h2, offsets, esrc, Wb + 32768,  b3, out, nullptr);
}